// Round 6
// baseline (429.478 us; speedup 1.0000x reference)
//
#include <hip/hip_runtime.h>

// RPN anchor-target assignment. B=8, A=184320, G=64.
// Outputs (flat float32, concatenated): labels[B*A], matched[B*A*4], max_iou[B*A].
// Requires A % 512 == 0 (184320 = 360*512).
//
// Sparse-mask strategy, 2 anchors/thread, single kernel:
// per block, build 4 quantized interval tables (u64[64]) over the 64 gts;
// each anchor gets a conservative superset mask of possibly-overlapping gts
// (4 LDS lookups + 3 ands), then runs the exact IEEE IoU loop only over mask
// bits (~11 avg). Skipped pairs have true iou==0, handled exactly by
// maxv init 0 / KEY_INIT. Column argmax via sparse LDS u64 atomicMax.
// Rule-1 fixup runs inline in the last finishing block (done-counter whose
// "zero" is the harness's deterministic 0xAA poison pattern).

constexpr int B = 8;
constexpr int G = 64;
constexpr int BLOCK = 256;
constexpr int APT = 2;                 // anchors per thread
constexpr int ABLK = BLOCK * APT;      // anchors per block
constexpr float IMG = 640.0f;
constexpr float FG_IOU = 0.7f;
constexpr float BG_IOU = 0.3f;
constexpr float SLACK = 1.0f;
// key(iou=0, anchor=0): correct for an all-zero column (numpy argmax = 0).
constexpr unsigned long long KEY_INIT = 0xFFFFFFFFull;
// d_ws is re-poisoned to 0xAA bytes before every launch (harness contract).
constexpr unsigned CTR_POISON = 0xAAAAAAAAu;

// ws layout: [0] u32 counter; [256..] u64 gkeys[B*G] (0xAA poison < 0 as i64 == -inf)

__global__ __launch_bounds__(BLOCK) void assign_main(
    const float4* __restrict__ anchors,   // [B*A] cxcywh
    const float4* __restrict__ gt,        // [B*G] xyxy
    float* __restrict__ L,                // labels out [B*A]
    float4* __restrict__ M,               // matched out [B*A]
    float* __restrict__ V,                // max_iou out [B*A]
    long long* __restrict__ gkeys,        // [B*G] global argmax keys (signed max)
    unsigned* __restrict__ counter,
    int A, int bpb, int nblocks) {
#pragma clang fp contract(off)
    __shared__ float4 sgt[G];
    __shared__ float sarea[G];
    __shared__ unsigned long long tab[4][G];  // 0:xlo 1:xhi 2:ylo 3:yhi
    __shared__ unsigned long long skey[G];
    __shared__ int amLast;
    __shared__ int tgtA[G];

    const int b = blockIdx.x / bpb;
    const int t = threadIdx.x;
    const int lane = t & 63;
    const int wv = t >> 6;
    const int base = (blockIdx.x % bpb) * ABLK;

    if (t < G) {
        float4 gb = gt[b * G + t];
        sgt[t] = gb;
        sarea[t] = (gb.z - gb.x) * (gb.w - gb.y);
        skey[t] = KEY_INIT;
    }
    __syncthreads();

    // ---- interval tables; wave wv builds table wv (wave-uniform comp/sense)
    // tab0 (xlo): gt.x0 < (s+1)*10 + SLACK   (superset of gx0 < ax1, s=strip(ax1))
    // tab1 (xhi): gt.x1 > s*10 - SLACK       (superset of gx1 > ax0, s=strip(ax0))
    // tab2 (ylo): gt.y0 < (s+1)*10 + SLACK
    // tab3 (yhi): gt.y1 > s*10 - SLACK
    {
        const int comp = (wv == 0) ? 0 : (wv == 1) ? 2 : (wv == 2) ? 1 : 3;
        const bool hi = (wv & 1) != 0;
        const float thr = hi ? (lane * 10.0f - SLACK)
                             : ((lane + 1) * 10.0f + SLACK);
        unsigned long long m = 0ull;
        for (int g = 0; g < G; ++g) {
            float c = ((const float*)&sgt[g])[comp];   // wave-uniform address
            bool in = hi ? (c > thr) : (c < thr);
            if (in) m |= (1ull << g);
        }
        tab[wv][lane] = m;
    }
    __syncthreads();

#pragma unroll
    for (int j = 0; j < APT; ++j) {
        const int a = base + j * BLOCK + t;
        const size_t idx = (size_t)b * A + a;
        float4 an = anchors[idx];
        float ax0 = an.x - 0.5f * an.z;
        float ay0 = an.y - 0.5f * an.w;
        float ax1 = an.x + 0.5f * an.z;
        float ay1 = an.y + 0.5f * an.w;
        float area_a = (ax1 - ax0) * (ay1 - ay0);

        int sx0 = (int)(ax0 * 0.1f); sx0 = sx0 < 0 ? 0 : (sx0 > 63 ? 63 : sx0);
        int sx1 = (int)(ax1 * 0.1f); sx1 = sx1 < 0 ? 0 : (sx1 > 63 ? 63 : sx1);
        int sy0 = (int)(ay0 * 0.1f); sy0 = sy0 < 0 ? 0 : (sy0 > 63 ? 63 : sy0);
        int sy1 = (int)(ay1 * 0.1f); sy1 = sy1 < 0 ? 0 : (sy1 > 63 ? 63 : sy1);

        unsigned long long mask = tab[0][sx1] & tab[1][sx0] & tab[2][sy1] & tab[3][sy0];

        float maxv = 0.0f;   // all-masked row => max_iou 0, argmax 0 (numpy exact)
        int maxg = 0;
        const unsigned long long inv_p =
            (unsigned long long)(0xFFFFFFFFu - (unsigned)a);

        while (mask) {
            const int g = __ffsll(mask) - 1;   // ascending g: strict > = first max
            mask &= mask - 1;
            float4 gb = sgt[g];
            float sa = sarea[g];
            float lx = fmaxf(ax0, gb.x);
            float ly = fmaxf(ay0, gb.y);
            float rx = fminf(ax1, gb.z);
            float ry = fminf(ay1, gb.w);
            float w = fmaxf(rx - lx, 0.0f);
            float h = fmaxf(ry - ly, 0.0f);
            float inter = w * h;
            float uni = area_a + sa - inter;
            float iou = inter / uni;           // IEEE div: bit-exact vs numpy

            bool better = iou > maxv;
            maxv = better ? iou : maxv;
            maxg = better ? g : maxg;

            if (iou > 0.0f) {                  // zero keys can never beat KEY_INIT
                unsigned long long key =
                    ((unsigned long long)__float_as_uint(iou) << 32) | inv_p;
                atomicMax(&skey[g], key);      // sparse: low contention
            }
        }

        bool fg = maxv > FG_IOU;
        bool bg = maxv < BG_IOU;
        bool cross = (ax0 < 0.0f) || (ay0 < 0.0f) || (ax1 > IMG) || (ay1 > IMG);

        L[idx] = cross ? -1.0f : (fg ? 1.0f : (bg ? 0.0f : -1.0f));
        M[idx] = fg ? sgt[maxg] : make_float4(0.0f, 0.0f, 0.0f, 0.0f);
        V[idx] = maxv;
    }

    __syncthreads();
    if (t < G) {
        // unconditional: every column must receive >= KEY_INIT (gkeys is poisoned)
        atomicMax(&gkeys[b * G + t], (long long)skey[t]);
    }

    // ---- inline rule-1 fixup in the last finishing block ----
    __threadfence();
    __syncthreads();
    if (t == 0) {
        unsigned prev = atomicAdd(counter, 1u);
        amLast = (prev == CTR_POISON + (unsigned)(nblocks - 1)) ? 1 : 0;
    }
    __syncthreads();
    if (amLast) {
        __threadfence();
        for (int bb = 0; bb < B; ++bb) {
            unsigned a = 0u;
            if (t < G) {
                unsigned long long key = (unsigned long long)__hip_atomic_load(
                    &gkeys[bb * G + t], __ATOMIC_RELAXED, __HIP_MEMORY_SCOPE_AGENT);
                a = 0xFFFFFFFFu - (unsigned)(key & 0xFFFFFFFFull);
                tgtA[t] = (int)a;
            }
            __syncthreads();
            if (t < G) {
                // numpy scatter = last-write-wins: write iff no later g' same anchor
                bool write = true;
                for (int g2 = t + 1; g2 < G; ++g2)
                    if (tgtA[g2] == (int)a) { write = false; break; }
                if (write) {
                    size_t idx2 = (size_t)bb * A + a;
                    float4 an2 = anchors[idx2];
                    float bx0 = an2.x - 0.5f * an2.z;
                    float by0 = an2.y - 0.5f * an2.w;
                    float bx1 = an2.x + 0.5f * an2.z;
                    float by1 = an2.y + 0.5f * an2.w;
                    bool cr = (bx0 < 0.0f) || (by0 < 0.0f) ||
                              (bx1 > IMG) || (by1 > IMG);
                    L[idx2] = cr ? -1.0f : 1.0f;   // rule1 overrides bg; cross wins
                    float v = __hip_atomic_load(&V[idx2], __ATOMIC_RELAXED,
                                                __HIP_MEMORY_SCOPE_AGENT);
                    if (!(v > FG_IOU)) M[idx2] = gt[bb * G + t];  // fg keeps rule-2 box
                }
            }
            __syncthreads();
        }
    }
}

extern "C" void kernel_launch(void* const* d_in, const int* in_sizes, int n_in,
                              void* d_out, int out_size, void* d_ws, size_t ws_size,
                              hipStream_t stream) {
    const float4* anchors = (const float4*)d_in[0];
    const float4* gt      = (const float4*)d_in[1];
    const int A = in_sizes[0] / (B * 4);

    float* out = (float*)d_out;
    float*  L = out;                                 // [B*A]
    float4* M = (float4*)(out + (size_t)B * A);      // [B*A] float4
    float*  V = out + (size_t)B * A * 5;             // [B*A]

    char* ws = (char*)d_ws;
    unsigned* counter = (unsigned*)ws;               // poison 0xAAAAAAAA == "zero"
    long long* gkeys  = (long long*)(ws + 256);      // poison 0xAA.. == -inf (i64)

    const int bpb = A / ABLK;                        // 184320/512 = 360
    const int nblocks = B * bpb;
    assign_main<<<nblocks, BLOCK, 0, stream>>>(anchors, gt, L, M, V, gkeys,
                                               counter, A, bpb, nblocks);
}

// Round 7
// 124.640 us; speedup vs baseline: 3.4458x; 3.4458x over previous
//
#include <hip/hip_runtime.h>

// RPN anchor-target assignment. B=8, A=184320, G=64.
// Outputs (flat float32, concatenated): labels[B*A], matched[B*A*4], max_iou[B*A].
// Requires A % 512 == 0 (184320 = 360*512).
//
// Sparse-mask strategy, 2 anchors/thread, separate kernels (NO device fences:
// R6 showed per-block __threadfence() == L2 flush per block == ~300us stall).
// Per batch, 4 quantized interval tables (u64[64]) over the 64 gts are built
// once by build_tables; each anchor gets a conservative superset mask of
// possibly-overlapping gts (4 LDS lookups + 3 ands), then runs the exact IEEE
// IoU loop only over mask bits (~11 avg). Skipped pairs have true iou==0,
// handled exactly by maxv init 0 / KEY_INIT. Column argmax via sparse LDS u64
// atomicMax, block->global via device atomicMax.

constexpr int B = 8;
constexpr int G = 64;
constexpr int BLOCK = 256;
constexpr int APT = 2;                 // anchors per thread
constexpr int ABLK = BLOCK * APT;      // anchors per block
constexpr float IMG = 640.0f;
constexpr float FG_IOU = 0.7f;
constexpr float BG_IOU = 0.3f;
constexpr float SLACK = 1.0f;
// key(iou=0, anchor=0): correct for an all-zero column (numpy argmax = 0).
constexpr unsigned long long KEY_INIT = 0xFFFFFFFFull;

// ws layout: [256]   u64 gkeys[B*G]   (0xAA poison < 0 as i64 == -inf)
//            [8192]  u64 tabs[B][4][G] (built by build_tables each launch)

// tab0 (xlo): gt.x0 < (s+1)*10 + SLACK   used at s=strip(ax1)  ⊇ gt.x0 < ax1
// tab1 (xhi): gt.x1 > s*10 - SLACK       used at s=strip(ax0)  ⊇ gt.x1 > ax0
// tab2 (ylo): gt.y0 < (s+1)*10 + SLACK   used at s=strip(ay1)  ⊇ gt.y0 < ay1
// tab3 (yhi): gt.y1 > s*10 - SLACK       used at s=strip(ay0)  ⊇ gt.y1 > ay0
__global__ __launch_bounds__(256) void build_tables(
    const float4* __restrict__ gt, unsigned long long* __restrict__ tabs) {
    __shared__ float4 sgt[G];
    const int b = blockIdx.x;
    const int t = threadIdx.x;
    if (t < G) sgt[t] = gt[b * G + t];
    __syncthreads();
    const int tabIdx = t >> 6;          // 0..3
    const int strip = t & 63;
    const int comp = (tabIdx == 0) ? 0 : (tabIdx == 1) ? 2 : (tabIdx == 2) ? 1 : 3;
    const bool hi = (tabIdx & 1) != 0;
    const float thr = hi ? (strip * 10.0f - SLACK)
                         : ((strip + 1) * 10.0f + SLACK);
    unsigned long long m = 0ull;
    for (int g = 0; g < G; ++g) {
        float c = ((const float*)&sgt[g])[comp];
        bool in = hi ? (c > thr) : (c < thr);
        if (in) m |= (1ull << g);
    }
    tabs[(b * 4 + tabIdx) * G + strip] = m;
}

__global__ __launch_bounds__(BLOCK) void assign_main(
    const float4* __restrict__ anchors,   // [B*A] cxcywh
    const float4* __restrict__ gt,        // [B*G] xyxy
    float* __restrict__ L,                // labels out [B*A]
    float4* __restrict__ M,               // matched out [B*A]
    float* __restrict__ V,                // max_iou out [B*A]
    long long* __restrict__ gkeys,        // [B*G] global argmax keys (signed max)
    const unsigned long long* __restrict__ tabs,
    int A, int bpb) {
#pragma clang fp contract(off)
    __shared__ float4 sgt[G];
    __shared__ float sarea[G];
    __shared__ unsigned long long tab[4][G];
    __shared__ unsigned long long skey[G];

    const int b = blockIdx.x / bpb;
    const int t = threadIdx.x;
    const int base = (blockIdx.x % bpb) * ABLK;

    if (t < G) {
        float4 gb = gt[b * G + t];
        sgt[t] = gb;
        sarea[t] = (gb.z - gb.x) * (gb.w - gb.y);
        skey[t] = KEY_INIT;
    }
    tab[t >> 6][t & 63] = tabs[b * 256 + t];   // 2 KB table: one u64 per thread
    __syncthreads();

#pragma unroll
    for (int j = 0; j < APT; ++j) {
        const int a = base + j * BLOCK + t;
        const size_t idx = (size_t)b * A + a;
        float4 an = anchors[idx];
        float ax0 = an.x - 0.5f * an.z;
        float ay0 = an.y - 0.5f * an.w;
        float ax1 = an.x + 0.5f * an.z;
        float ay1 = an.y + 0.5f * an.w;
        float area_a = (ax1 - ax0) * (ay1 - ay0);

        int sx0 = (int)(ax0 * 0.1f); sx0 = sx0 < 0 ? 0 : (sx0 > 63 ? 63 : sx0);
        int sx1 = (int)(ax1 * 0.1f); sx1 = sx1 < 0 ? 0 : (sx1 > 63 ? 63 : sx1);
        int sy0 = (int)(ay0 * 0.1f); sy0 = sy0 < 0 ? 0 : (sy0 > 63 ? 63 : sy0);
        int sy1 = (int)(ay1 * 0.1f); sy1 = sy1 < 0 ? 0 : (sy1 > 63 ? 63 : sy1);

        unsigned long long mask =
            tab[0][sx1] & tab[1][sx0] & tab[2][sy1] & tab[3][sy0];

        float maxv = 0.0f;   // all-masked row => max_iou 0, argmax 0 (numpy exact)
        int maxg = 0;
        const unsigned long long inv_p =
            (unsigned long long)(0xFFFFFFFFu - (unsigned)a);

        while (mask) {
            const int g = __ffsll(mask) - 1;   // ascending g: strict > = first max
            mask &= mask - 1;
            float4 gb = sgt[g];
            float sa = sarea[g];
            float lx = fmaxf(ax0, gb.x);
            float ly = fmaxf(ay0, gb.y);
            float rx = fminf(ax1, gb.z);
            float ry = fminf(ay1, gb.w);
            float w = fmaxf(rx - lx, 0.0f);
            float h = fmaxf(ry - ly, 0.0f);
            float inter = w * h;
            float uni = area_a + sa - inter;
            float iou = inter / uni;           // IEEE div: bit-exact vs numpy

            bool better = iou > maxv;
            maxv = better ? iou : maxv;
            maxg = better ? g : maxg;

            if (iou > 0.0f) {                  // zero keys never beat KEY_INIT
                unsigned long long key =
                    ((unsigned long long)__float_as_uint(iou) << 32) | inv_p;
                atomicMax(&skey[g], key);      // sparse: low contention
            }
        }

        bool fg = maxv > FG_IOU;
        bool bg = maxv < BG_IOU;
        bool cross = (ax0 < 0.0f) || (ay0 < 0.0f) || (ax1 > IMG) || (ay1 > IMG);

        L[idx] = cross ? -1.0f : (fg ? 1.0f : (bg ? 0.0f : -1.0f));
        M[idx] = fg ? sgt[maxg] : make_float4(0.0f, 0.0f, 0.0f, 0.0f);
        V[idx] = maxv;
    }

    __syncthreads();
    if (t < G) {
        // unconditional: every column must receive >= KEY_INIT (gkeys poisoned)
        atomicMax(&gkeys[b * G + t], (long long)skey[t]);
    }
}

// Rule 1 fixup: one block per batch, thread per gt. numpy scatter is
// last-write-wins; thread g writes only if no later g' targets the same anchor.
__global__ void fixup(
    const float4* __restrict__ anchors,
    const float4* __restrict__ gt,
    const long long* __restrict__ gkeys,
    float* __restrict__ L,
    float4* __restrict__ M,
    const float* __restrict__ V,
    int A) {
#pragma clang fp contract(off)
    const int b = blockIdx.x;
    const int g = threadIdx.x;
    __shared__ int tgt[G];

    unsigned long long key = (unsigned long long)gkeys[b * G + g];
    unsigned int a = 0xFFFFFFFFu - (unsigned int)(key & 0xFFFFFFFFull);
    tgt[g] = (int)a;
    __syncthreads();

    bool write = true;
    for (int g2 = g + 1; g2 < G; ++g2)
        if (tgt[g2] == (int)a) { write = false; break; }
    if (!write) return;

    const size_t idx = (size_t)b * A + a;
    float4 an = anchors[idx];
    float ax0 = an.x - 0.5f * an.z;
    float ay0 = an.y - 0.5f * an.w;
    float ax1 = an.x + 0.5f * an.z;
    float ay1 = an.y + 0.5f * an.w;
    bool cross = (ax0 < 0.0f) || (ay0 < 0.0f) || (ax1 > IMG) || (ay1 > IMG);
    // Rule 1 label=1 overrides rule-3 bg; cross filter still wins.
    L[idx] = cross ? -1.0f : 1.0f;
    // Rule 2 (fg) overrides rule 1's matched box; otherwise rule 1 assigns gt[g].
    if (!(V[idx] > FG_IOU)) M[idx] = gt[b * G + g];
}

extern "C" void kernel_launch(void* const* d_in, const int* in_sizes, int n_in,
                              void* d_out, int out_size, void* d_ws, size_t ws_size,
                              hipStream_t stream) {
    const float4* anchors = (const float4*)d_in[0];
    const float4* gt      = (const float4*)d_in[1];
    const int A = in_sizes[0] / (B * 4);

    float* out = (float*)d_out;
    float*  L = out;                                 // [B*A]
    float4* M = (float4*)(out + (size_t)B * A);      // [B*A] float4
    float*  V = out + (size_t)B * A * 5;             // [B*A]

    char* ws = (char*)d_ws;
    long long* gkeys = (long long*)(ws + 256);       // poison 0xAA.. == -inf (i64)
    unsigned long long* tabs = (unsigned long long*)(ws + 8192);  // B*4*64 u64

    const int bpb = A / ABLK;                        // 184320/512 = 360
    build_tables<<<B, 256, 0, stream>>>(gt, tabs);
    assign_main<<<B * bpb, BLOCK, 0, stream>>>(anchors, gt, L, M, V, gkeys,
                                               tabs, A, bpb);
    fixup<<<B, G, 0, stream>>>(anchors, gt, gkeys, L, M, V, A);
}

// Round 8
// 122.204 us; speedup vs baseline: 3.5144x; 1.0199x over previous
//
#include <hip/hip_runtime.h>

// RPN anchor-target assignment. B=8, A=184320, G=64.
// Outputs (flat float32, concatenated): labels[B*A], matched[B*A*4], max_iou[B*A].
// Requires A % 512 == 0 (184320 = 360*512).
//
// Sparse-mask strategy, 2 anchors/thread, 3 kernels (no device fences — R6
// showed per-block __threadfence() is an L2-flush-scale stall on CDNA4).
// Per batch, 4 quantized interval tables (u64[128], 5px strips) over the 64
// gts are built once; each anchor gets a conservative superset mask of
// possibly-overlapping gts (4 LDS lookups + 3 ands), then runs the exact IEEE
// IoU loop only over mask bits (~10 avg). Skipped pairs have true iou==0,
// handled exactly by maxv init 0 / KEY_INIT. gt coords stored SoA in LDS
// (scalar b32 reads ≈ conflict-free vs 8-way-conflicted b128 gather, R7 PMC:
// 3.2M conflict cycles). Column argmax via LDS u64 atomicMax (branchless
// zero-key for iou==0), block->global via device atomicMax.

constexpr int B = 8;
constexpr int G = 64;
constexpr int BLOCK = 256;
constexpr int APT = 2;                 // anchors per thread
constexpr int ABLK = BLOCK * APT;      // anchors per block
constexpr int NSTRIP = 128;            // 5px strips
constexpr float STRIP_SCALE = 0.2f;
constexpr float STRIP_W = 5.0f;
constexpr float IMG = 640.0f;
constexpr float FG_IOU = 0.7f;
constexpr float BG_IOU = 0.3f;
constexpr float SLACK = 1.0f;
// key(iou=0, anchor=0): correct for an all-zero column (numpy argmax = 0).
constexpr unsigned long long KEY_INIT = 0xFFFFFFFFull;

// ws layout: [256]   u64 gkeys[B*G]      (0xAA poison < 0 as i64 == -inf)
//            [8192]  u64 tabs[B][4][128] (built by build_tables each launch)

// tab0 (xlo): gt.x0 < (s+1)*5 + SLACK   used at s=strip(ax1)  ⊇ gt.x0 < ax1
// tab1 (xhi): gt.x1 > s*5 - SLACK       used at s=strip(ax0)  ⊇ gt.x1 > ax0
// tab2 (ylo): gt.y0 < (s+1)*5 + SLACK   used at s=strip(ay1)  ⊇ gt.y0 < ay1
// tab3 (yhi): gt.y1 > s*5 - SLACK       used at s=strip(ay0)  ⊇ gt.y1 > ay0
__global__ __launch_bounds__(512) void build_tables(
    const float4* __restrict__ gt, unsigned long long* __restrict__ tabs) {
    __shared__ float4 sgt[G];
    const int b = blockIdx.x;
    const int t = threadIdx.x;          // 0..511 = tabIdx*128 + strip
    if (t < G) sgt[t] = gt[b * G + t];
    __syncthreads();
    const int tabIdx = t >> 7;
    const int strip = t & 127;
    const int comp = (tabIdx == 0) ? 0 : (tabIdx == 1) ? 2 : (tabIdx == 2) ? 1 : 3;
    const bool hi = (tabIdx & 1) != 0;
    const float thr = hi ? (strip * STRIP_W - SLACK)
                         : ((strip + 1) * STRIP_W + SLACK);
    unsigned long long m = 0ull;
    for (int g = 0; g < G; ++g) {
        float c = ((const float*)&sgt[g])[comp];
        bool in = hi ? (c > thr) : (c < thr);
        if (in) m |= (1ull << g);
    }
    tabs[(size_t)b * 512 + t] = m;
}

__global__ __launch_bounds__(BLOCK) void assign_main(
    const float4* __restrict__ anchors,   // [B*A] cxcywh
    const float4* __restrict__ gt,        // [B*G] xyxy
    float* __restrict__ L,                // labels out [B*A]
    float4* __restrict__ M,               // matched out [B*A]
    float* __restrict__ V,                // max_iou out [B*A]
    long long* __restrict__ gkeys,        // [B*G] global argmax keys (signed max)
    const unsigned long long* __restrict__ tabs,
    int A, int bpb) {
#pragma clang fp contract(off)
    __shared__ float4 sgt[G];             // AoS copy for the rare fg epilogue read
    __shared__ float sgx0[G], sgy0[G], sgx1[G], sgy1[G], sga[G];  // SoA: b32 reads
    __shared__ unsigned long long tab[4][NSTRIP];
    __shared__ unsigned long long skey[G];

    const int b = blockIdx.x / bpb;
    const int t = threadIdx.x;
    const int base = (blockIdx.x % bpb) * ABLK;

    if (t < G) {
        float4 gb = gt[b * G + t];
        sgt[t] = gb;
        sgx0[t] = gb.x; sgy0[t] = gb.y; sgx1[t] = gb.z; sgy1[t] = gb.w;
        sga[t] = (gb.z - gb.x) * (gb.w - gb.y);
        skey[t] = KEY_INIT;
    }
    {   // 4 KB table: two u64 per thread
        unsigned long long* tflat = &tab[0][0];
        tflat[t]       = tabs[(size_t)b * 512 + t];
        tflat[t + 256] = tabs[(size_t)b * 512 + 256 + t];
    }
    __syncthreads();

#pragma unroll
    for (int j = 0; j < APT; ++j) {
        const int a = base + j * BLOCK + t;
        const size_t idx = (size_t)b * A + a;
        float4 an = anchors[idx];
        float ax0 = an.x - 0.5f * an.z;
        float ay0 = an.y - 0.5f * an.w;
        float ax1 = an.x + 0.5f * an.z;
        float ay1 = an.y + 0.5f * an.w;
        float area_a = (ax1 - ax0) * (ay1 - ay0);   // must match numpy (corner-derived)

        int sx0 = (int)(ax0 * STRIP_SCALE); sx0 = sx0 < 0 ? 0 : (sx0 > 127 ? 127 : sx0);
        int sx1 = (int)(ax1 * STRIP_SCALE); sx1 = sx1 < 0 ? 0 : (sx1 > 127 ? 127 : sx1);
        int sy0 = (int)(ay0 * STRIP_SCALE); sy0 = sy0 < 0 ? 0 : (sy0 > 127 ? 127 : sy0);
        int sy1 = (int)(ay1 * STRIP_SCALE); sy1 = sy1 < 0 ? 0 : (sy1 > 127 ? 127 : sy1);

        unsigned long long mask =
            tab[0][sx1] & tab[1][sx0] & tab[2][sy1] & tab[3][sy0];

        float maxv = 0.0f;   // all-masked row => max_iou 0, argmax 0 (numpy exact)
        int maxg = 0;
        const unsigned long long inv_p =
            (unsigned long long)(0xFFFFFFFFu - (unsigned)a);

        // two u32 half-loops, ascending g => strict > keeps numpy first-max
        unsigned mlo = (unsigned)mask;
        unsigned mhi = (unsigned)(mask >> 32);
        auto half = [&](unsigned m, int gbase) {
            while (m) {
                const int g = gbase + __builtin_ctz(m);
                m &= m - 1;
                float gx0 = sgx0[g], gy0 = sgy0[g];
                float gx1 = sgx1[g], gy1 = sgy1[g];
                float sa = sga[g];
                float lx = fmaxf(ax0, gx0);
                float ly = fmaxf(ay0, gy0);
                float rx = fminf(ax1, gx1);
                float ry = fminf(ay1, gy1);
                float w = fmaxf(rx - lx, 0.0f);
                float h = fmaxf(ry - ly, 0.0f);
                float inter = w * h;
                float uni = area_a + sa - inter;
                float iou = inter / uni;         // IEEE div: bit-exact vs numpy

                bool better = iou > maxv;
                maxv = better ? iou : maxv;
                maxg = better ? g : maxg;

                unsigned long long key =
                    ((unsigned long long)__float_as_uint(iou) << 32) | inv_p;
                key = (iou > 0.0f) ? key : 0ull; // zero keys never beat KEY_INIT
                atomicMax(&skey[g], key);        // branchless, sparse contention
            }
        };
        half(mlo, 0);
        half(mhi, 32);

        bool fg = maxv > FG_IOU;
        bool bg = maxv < BG_IOU;
        bool cross = (ax0 < 0.0f) || (ay0 < 0.0f) || (ax1 > IMG) || (ay1 > IMG);

        L[idx] = cross ? -1.0f : (fg ? 1.0f : (bg ? 0.0f : -1.0f));
        float4 m = make_float4(0.0f, 0.0f, 0.0f, 0.0f);
        if (fg) m = sgt[maxg];                   // rare: usually whole-wave skipped
        M[idx] = m;
        V[idx] = maxv;
    }

    __syncthreads();
    if (t < G) {
        // unconditional: every column must receive >= KEY_INIT (gkeys poisoned)
        atomicMax(&gkeys[b * G + t], (long long)skey[t]);
    }
}

// Rule 1 fixup: one block per batch, thread per gt. numpy scatter is
// last-write-wins; thread g writes only if no later g' targets the same anchor.
__global__ void fixup(
    const float4* __restrict__ anchors,
    const float4* __restrict__ gt,
    const long long* __restrict__ gkeys,
    float* __restrict__ L,
    float4* __restrict__ M,
    const float* __restrict__ V,
    int A) {
#pragma clang fp contract(off)
    const int b = blockIdx.x;
    const int g = threadIdx.x;
    __shared__ int tgt[G];

    unsigned long long key = (unsigned long long)gkeys[b * G + g];
    unsigned int a = 0xFFFFFFFFu - (unsigned int)(key & 0xFFFFFFFFull);
    tgt[g] = (int)a;
    __syncthreads();

    bool write = true;
    for (int g2 = g + 1; g2 < G; ++g2)
        if (tgt[g2] == (int)a) { write = false; break; }
    if (!write) return;

    const size_t idx = (size_t)b * A + a;
    float4 an = anchors[idx];
    float ax0 = an.x - 0.5f * an.z;
    float ay0 = an.y - 0.5f * an.w;
    float ax1 = an.x + 0.5f * an.z;
    float ay1 = an.y + 0.5f * an.w;
    bool cross = (ax0 < 0.0f) || (ay0 < 0.0f) || (ax1 > IMG) || (ay1 > IMG);
    // Rule 1 label=1 overrides rule-3 bg; cross filter still wins.
    L[idx] = cross ? -1.0f : 1.0f;
    // Rule 2 (fg) overrides rule 1's matched box; otherwise rule 1 assigns gt[g].
    if (!(V[idx] > FG_IOU)) M[idx] = gt[b * G + g];
}

extern "C" void kernel_launch(void* const* d_in, const int* in_sizes, int n_in,
                              void* d_out, int out_size, void* d_ws, size_t ws_size,
                              hipStream_t stream) {
    const float4* anchors = (const float4*)d_in[0];
    const float4* gt      = (const float4*)d_in[1];
    const int A = in_sizes[0] / (B * 4);

    float* out = (float*)d_out;
    float*  L = out;                                 // [B*A]
    float4* M = (float4*)(out + (size_t)B * A);      // [B*A] float4
    float*  V = out + (size_t)B * A * 5;             // [B*A]

    char* ws = (char*)d_ws;
    long long* gkeys = (long long*)(ws + 256);       // poison 0xAA.. == -inf (i64)
    unsigned long long* tabs = (unsigned long long*)(ws + 8192);  // B*4*128 u64

    const int bpb = A / ABLK;                        // 184320/512 = 360
    build_tables<<<B, 512, 0, stream>>>(gt, tabs);
    assign_main<<<B * bpb, BLOCK, 0, stream>>>(anchors, gt, L, M, V, gkeys,
                                               tabs, A, bpb);
    fixup<<<B, G, 0, stream>>>(anchors, gt, gkeys, L, M, V, A);
}